// Round 7
// baseline (293.365 us; speedup 1.0000x reference)
//
#include <hip/hip_runtime.h>

#define NPTS 8192
#define KNNK 16
#define NSLOT 17          // keep 17, fp64-refine drops the worst -> robust 16-set
#define LEAKY 0.1f

typedef short bf16x8 __attribute__((ext_vector_type(8)));
typedef float f32x4  __attribute__((ext_vector_type(4)));

// ---- knn config ----
#define KTH    1024            // threads/block (16 waves)
#define QPB    128             // queries per block -> grid 256
#define HALF   4096            // candidates staged per half
#define CT_H   (HALF / 16)     // 256 c-tiles per half
#define BUFCAP 64              // survivor buffer per query (grown 48->64)
#define DELTA  0.0078125f      // collect margin 2^-7 >> 2x bf16-split error

// ---------------------------------------------------------------------------
// R11: MFMA distances. R10 counters: knn VALUBusy 75%, MfmaUtil 0% -> the
// 537M-pair distance stream is VALU-issue-bound with the matrix pipe idle.
// d'(q,c) = |c|^2 - 2q.c via 2 MFMAs: B (candidate, LDS 16B entry) packs
// bf16 [ch3,|c|2h, cl3,|c|2l]; A1 = [-2qh,1,-2ql,1], A2 = [-2ql,0,-2qh,0]
// (quad0 lanes; quads1-3 zero via reg-zero / zero-block broadcast). Then
// mfma(A1,B)+mfma(A2,B) = all 4 hi/lo cross terms + |c|^2 (1.0 slots) = d'
// with error <= ~1e-3. Threshold on d~ (merged 64->32-chunk min-2 table,
// rank-17), phase 2 collects d~ <= tq+DELTA (provable superset of the true
// top-17), REPAIR pass recomputes exact fp32 d' (bit-identical formula to
// R9) for <=64 survivors, phase 3 top-17 + fp64 refine unchanged -> output
// identical to R9's passing kernel. Fragment layouts copied from the
// harness-verified feat_kernel (A: row=lane&15,k=quad*8; C: col=lane&15,
// row=quad*4+r). Hot loop: 1 ds_read_b128 + 4 MFMA + 16 min-ops per
// 512 pairs (~0.1 VALU/pair vs 5.9).
// ---------------------------------------------------------------------------

__device__ __forceinline__ unsigned short bfh(float f) {
    return (unsigned short)(__float_as_uint(f) >> 16);
}
__device__ __forceinline__ float bfhf(float f) {
    return __uint_as_float(__float_as_uint(f) & 0xffff0000u);
}

__global__ __launch_bounds__(KTH, 4) void knn_kernel(
    const float* __restrict__ pc1, const float* __restrict__ pc2,
    int* __restrict__ knn_out)
{
    __shared__ uint4 cbuf[HALF];                 // 64 KB staged candidates
    __shared__ float sbuf[QPB][2 * BUFCAP];      // 64 KB: raw table / surv d+idx
    __shared__ float sthr[QPB];
    __shared__ int   scnt[QPB];
    __shared__ uint4 zb;                         // 16B zero block (broadcast)

    const int t   = threadIdx.x;
    const int q0  = blockIdx.x * QPB;
    const int dir = q0 >> 14;
    const int b   = (q0 >> 13) & 1;

    const float* __restrict__ pq    = dir ? pc2 : pc1;
    const float* __restrict__ pcand = dir ? pc1 : pc2;
    const float* __restrict__ csrc  = pcand + (size_t)b * NPTS * 3;
    const int n0 = q0 & (NPTS - 1);

    const int lane = t & 63;
    const int wave = t >> 6;
    const int col  = lane & 15;
    const int quad = lane >> 4;
    const int qg   = wave & 3;     // q-group: q-tiles 2qg, 2qg+1
    const int cs   = wave >> 2;    // c-slice 0..3

    if (t < QPB) scnt[t] = 0;
    if (t == 0)  { zb.x = 0; zb.y = 0; zb.z = 0; zb.w = 0; }

    // ---- A-frags: per wave, 2 q-tiles, quad0 lanes carry k0..7 -------------
    bf16x8 A1[2], A2[2];
    #pragma unroll
    for (int j = 0; j < 2; ++j) {
        union { unsigned short u[8]; bf16x8 v; } a1u, a2u;
        #pragma unroll
        for (int e = 0; e < 8; ++e) { a1u.u[e] = 0; a2u.u[e] = 0; }
        if (quad == 0) {
            const int aq = n0 + (2 * qg + j) * 16 + col;   // A row = lane&15
            const float* qp = pq + ((size_t)b * NPTS + aq) * 3;
            const float fx = -2.0f * qp[0];
            const float fy = -2.0f * qp[1];
            const float fz = -2.0f * qp[2];
            const unsigned short hx = bfh(fx), hy = bfh(fy), hz = bfh(fz);
            const unsigned short lx = bfh(fx - bfhf(fx));
            const unsigned short ly = bfh(fy - bfhf(fy));
            const unsigned short lz = bfh(fz - bfhf(fz));
            a1u.u[0] = hx; a1u.u[1] = hy; a1u.u[2] = hz; a1u.u[3] = 0x3F80;
            a1u.u[4] = lx; a1u.u[5] = ly; a1u.u[6] = lz; a1u.u[7] = 0x3F80;
            a2u.u[0] = lx; a2u.u[1] = ly; a2u.u[2] = lz; a2u.u[3] = 0;
            a2u.u[4] = hx; a2u.u[5] = hy; a2u.u[6] = hz; a2u.u[7] = 0;
        }
        A1[j] = a1u.v; A2[j] = a2u.v;
    }

    // ---- staging: half h -> cbuf as [ch3,cnh, cl3,cnl] bf16 ----------------
    auto stage = [&](int h) {
        for (int i = t; i < HALF; i += KTH) {
            const int gi = h * HALF + i;
            const float cx = csrc[3 * gi];
            const float cy = csrc[3 * gi + 1];
            const float cz = csrc[3 * gi + 2];
            const float cn = fmaf(cx, cx, fmaf(cy, cy, cz * cz));
            const unsigned int hx = bfh(cx), hy = bfh(cy), hz = bfh(cz), hn = bfh(cn);
            const unsigned int lx = bfh(cx - bfhf(cx));
            const unsigned int ly = bfh(cy - bfhf(cy));
            const unsigned int lz = bfh(cz - bfhf(cz));
            const unsigned int ln = bfh(cn - bfhf(cn));
            uint4 e;
            e.x = hx | (hy << 16);    // k0=chx k1=chy
            e.y = hz | (hn << 16);    // k2=chz k3=cnh
            e.z = lx | (ly << 16);    // k4=clx k5=cly
            e.w = lz | (ln << 16);    // k6=clz k7=cnl
            cbuf[i] = e;
        }
    };

    // B-frag address: quad0 walks candidate entries; quads1-3 broadcast zero
    const int  bstep = (quad == 0) ? 4 * 16 * (int)sizeof(uint4) : 0;
    const char* bbase0 = (quad == 0)
        ? (const char*)&cbuf[cs * 16 + col] : (const char*)&zb;

    // ---- phase 1: min-2 trackers over d~ (MFMA) ----------------------------
    float m1t[2][4], m2t[2][4];
    #pragma unroll
    for (int j = 0; j < 2; ++j)
        #pragma unroll
        for (int r = 0; r < 4; ++r) { m1t[j][r] = 3.0e38f; m2t[j][r] = 3.0e38f; }

    #pragma unroll
    for (int h = 0; h < 2; ++h) {
        __syncthreads();               // cbuf free to overwrite
        stage(h);
        __syncthreads();
        const char* bp = bbase0;
        #pragma unroll 2
        for (int ct = cs; ct < CT_H; ct += 4) {
            const bf16x8 B = *(const bf16x8*)bp; bp += bstep;
            #pragma unroll
            for (int j = 0; j < 2; ++j) {
                f32x4 d = {0.f, 0.f, 0.f, 0.f};
                d = __builtin_amdgcn_mfma_f32_16x16x32_bf16(A1[j], B, d, 0, 0, 0);
                d = __builtin_amdgcn_mfma_f32_16x16x32_bf16(A2[j], B, d, 0, 0, 0);
                #pragma unroll
                for (int r = 0; r < 4; ++r) {
                    m2t[j][r] = __builtin_amdgcn_fmed3f(d[r], m1t[j][r], m2t[j][r]);
                    m1t[j][r] = fminf(m1t[j][r], d[r]);
                }
            }
        }
    }
    __syncthreads();

    // ---- raw table: 64 chunks x min-2 = 128 values per query ---------------
    #pragma unroll
    for (int j = 0; j < 2; ++j)
        #pragma unroll
        for (int r = 0; r < 4; ++r) {
            const int row = (2 * qg + j) * 16 + quad * 4 + r;
            const int ch  = cs * 16 + col;
            sbuf[row][2 * ch]     = m1t[j][r];
            sbuf[row][2 * ch + 1] = m2t[j][r];
        }
    __syncthreads();

    // ---- merge 64->32 chunks (valid min-2 of unions), rank-17 --------------
    float* mt = (float*)cbuf;          // 128 q x 64 floats = 32 KB (cbuf reuse)
    for (int tau = t; tau < QPB * 32; tau += KTH) {
        const int q = tau >> 5, j = tau & 31;
        const float a1 = sbuf[q][2 * j],        a2 = sbuf[q][2 * j + 1];
        const float b1 = sbuf[q][2 * (j + 32)], b2 = sbuf[q][2 * (j + 32) + 1];
        mt[q * 64 + 2 * j]     = fminf(a1, b1);
        mt[q * 64 + 2 * j + 1] = fminf(fmaxf(a1, b1), fminf(a2, b2));
    }
    __syncthreads();
    for (int tau = t; tau < QPB * 32; tau += KTH) {
        const int q = tau >> 5, j = tau & 31;
        const float v1 = mt[q * 64 + 2 * j], v2 = mt[q * 64 + 2 * j + 1];
        int lt1 = 0, eq1 = 0, lt2 = 0, eq2 = 0;
        #pragma unroll
        for (int c = 0; c < 64; c += 2) {
            const float2 vp = *(const float2*)&mt[q * 64 + c];
            lt1 += (vp.x < v1) ? 1 : 0;  eq1 += (vp.x == v1) ? 1 : 0;
            lt1 += (vp.y < v1) ? 1 : 0;  eq1 += (vp.y == v1) ? 1 : 0;
            lt2 += (vp.x < v2) ? 1 : 0;  eq2 += (vp.x == v2) ? 1 : 0;
            lt2 += (vp.y < v2) ? 1 : 0;  eq2 += (vp.y == v2) ? 1 : 0;
        }
        if (lt1 <= 16 && lt1 + eq1 > 16) sthr[q] = v1;
        if (lt2 <= 16 && lt2 + eq2 > 16) sthr[q] = v2;
    }
    __syncthreads();

    float tq[2][4];
    #pragma unroll
    for (int j = 0; j < 2; ++j)
        #pragma unroll
        for (int r = 0; r < 4; ++r)
            tq[j][r] = sthr[(2 * qg + j) * 16 + quad * 4 + r] + DELTA;

    // ---- phase 2: collect survivor indices (d~ <= tq+DELTA) ----------------
    #pragma unroll
    for (int h = 0; h < 2; ++h) {
        __syncthreads();               // mt / previous half dead
        stage(h);
        __syncthreads();
        const char* bp = bbase0;
        #pragma unroll 2
        for (int ct = cs; ct < CT_H; ct += 4) {
            const bf16x8 B = *(const bf16x8*)bp; bp += bstep;
            #pragma unroll
            for (int j = 0; j < 2; ++j) {
                f32x4 d = {0.f, 0.f, 0.f, 0.f};
                d = __builtin_amdgcn_mfma_f32_16x16x32_bf16(A1[j], B, d, 0, 0, 0);
                d = __builtin_amdgcn_mfma_f32_16x16x32_bf16(A2[j], B, d, 0, 0, 0);
                const float g = fmaxf(fmaxf(tq[j][0] - d[0], tq[j][1] - d[1]),
                                      fmaxf(tq[j][2] - d[2], tq[j][3] - d[3]));
                if (g >= 0.f) {
                    #pragma unroll
                    for (int r = 0; r < 4; ++r) {
                        if (d[r] <= tq[j][r]) {
                            const int q = (2 * qg + j) * 16 + quad * 4 + r;
                            const int pos = atomicAdd(&scnt[q], 1);
                            if (pos < BUFCAP)
                                ((int*)&sbuf[q][BUFCAP])[pos] =
                                    h * HALF + ct * 16 + col;
                        }
                    }
                }
            }
        }
    }
    __syncthreads();

    // ---- repair: exact fp32 d' for survivors (bit-identical to R9) ---------
    {
        const int rq = t >> 3;                 // 8 threads per query
        const int nc = min(scnt[rq], BUFCAP);
        const float* qp = pq + ((size_t)b * NPTS + n0 + rq) * 3;
        const float q2x = -2.0f * qp[0];
        const float q2y = -2.0f * qp[1];
        const float q2z = -2.0f * qp[2];
        for (int s = t & 7; s < nc; s += 8) {
            const int id = ((int*)&sbuf[rq][BUFCAP])[s];
            const float cx = csrc[3 * id], cy = csrc[3 * id + 1], cz = csrc[3 * id + 2];
            const float cn = fmaf(cx, cx, fmaf(cy, cy, cz * cz));
            sbuf[rq][s] = fmaf(q2x, cx, fmaf(q2y, cy, fmaf(q2z, cz, cn)));
        }
    }
    __syncthreads();

    // ---- phase 3: exact top-17 of survivors + fp64 refine ------------------
    if (t < QPB) {
        const int nc = min(scnt[t], BUFCAP);

        float dist[NSLOT];   // sorted descending by (d, idx); dist[0] = worst
        int   ind[NSLOT];
        #pragma unroll
        for (int i = 0; i < NSLOT; ++i) { dist[i] = 3.0e38f; ind[i] = 0x7fffffff; }

        for (int s = 0; s < nc; ++s) {
            const float d  = sbuf[t][s];
            const int   id = ((int*)&sbuf[t][BUFCAP])[s];
            const bool better0 = (d < dist[0]) || (d == dist[0] && id < ind[0]);
            if (better0) {
                bool cprev = true;
                #pragma unroll
                for (int i = 0; i < NSLOT - 1; ++i) {
                    const bool ci = (d < dist[i + 1]) ||
                                    (d == dist[i + 1] && id < ind[i + 1]);
                    const float nv = ci ? dist[i + 1] : (cprev ? d  : dist[i]);
                    const int   ni = ci ? ind[i + 1]  : (cprev ? id : ind[i]);
                    dist[i] = nv; ind[i] = ni;
                    cprev = ci;
                }
                if (cprev) { dist[NSLOT - 1] = d; ind[NSLOT - 1] = id; }
            }
        }

        const float* qpp = pq + ((size_t)b * NPTS + n0 + t) * 3;
        const double dqx = (double)qpp[0], dqy = (double)qpp[1], dqz = (double)qpp[2];
        double dd[NSLOT];
        #pragma unroll
        for (int i = 0; i < NSLOT; ++i) {
            const int id = ind[i];
            const float* cp = csrc + 3 * (size_t)id;
            const double dx = (double)cp[0] - dqx;
            const double dy = (double)cp[1] - dqy;
            const double dz = (double)cp[2] - dqz;
            dd[i] = dx * dx + dy * dy + dz * dz;
        }
        int worst = 0; double wd = dd[0];
        #pragma unroll
        for (int i = 1; i < NSLOT; ++i) { if (dd[i] > wd) { wd = dd[i]; worst = i; } }

        int* outp = knn_out + (size_t)(q0 + t) * KNNK;
        int slot = 0;
        #pragma unroll
        for (int i = 0; i < NSLOT; ++i) {
            if (i != worst) outp[slot++] = ind[i];
        }
    }
}

// ---------------------------------------------------------------------------
// Kernel 2 (R10, unchanged): feature MLP, 16 points/block in 4 pipelined
// groups of 4 with register-staged gather overlap.
// ---------------------------------------------------------------------------
#define PTS 16     // points per block
#define NG  4      // groups of 4 points

__device__ __forceinline__ unsigned int packhl(float f) {
    const unsigned int u = __float_as_uint(f);
    const unsigned int h = u & 0xffff0000u;
    const float lf = f - __uint_as_float(h);
    return h | (__float_as_uint(lf) >> 16);
}

__device__ __forceinline__ void build_b(const float* __restrict__ wrow,
                                        bf16x8* hi, bf16x8* lo) {
    union { unsigned int u[4]; bf16x8 v; } H, L;
    #pragma unroll
    for (int r = 0; r < 4; ++r) {
        const float f0 = wrow[2 * r], f1 = wrow[2 * r + 1];
        const unsigned int h0 = __float_as_uint(f0) & 0xffff0000u;
        const unsigned int h1 = __float_as_uint(f1) & 0xffff0000u;
        const float l0 = f0 - __uint_as_float(h0);
        const float l1 = f1 - __uint_as_float(h1);
        H.u[r] = h1 | (h0 >> 16);
        L.u[r] = (__float_as_uint(l1) & 0xffff0000u) | (__float_as_uint(l0) >> 16);
    }
    *hi = H.v; *lo = L.v;
}

__device__ __forceinline__ void unpack_a(const unsigned int* __restrict__ Tu,
                                         bf16x8* hi, bf16x8* lo) {
    union { unsigned int u[4]; bf16x8 v; } H, L;
    #pragma unroll
    for (int r = 0; r < 4; ++r) {
        const unsigned int a = Tu[2 * r + 1], bb = Tu[2 * r];
        H.u[r] = __builtin_amdgcn_perm(a, bb, 0x07060302u);  // [a.hi16 : b.hi16]
        L.u[r] = __builtin_amdgcn_perm(a, bb, 0x05040100u);  // [a.lo16 : b.lo16]
    }
    *hi = H.v; *lo = L.v;
}

__device__ __forceinline__ f32x4 mfma3(f32x4 acc, bf16x8 ah, bf16x8 al,
                                       bf16x8 bh, bf16x8 bl) {
    acc = __builtin_amdgcn_mfma_f32_16x16x32_bf16(ah, bl, acc, 0, 0, 0);
    acc = __builtin_amdgcn_mfma_f32_16x16x32_bf16(al, bh, acc, 0, 0, 0);
    acc = __builtin_amdgcn_mfma_f32_16x16x32_bf16(ah, bh, acc, 0, 0, 0);
    return acc;
}

__global__ __launch_bounds__(256, 4) void feat_kernel(
    const float* __restrict__ pc1, const float* __restrict__ pc2,
    const float* __restrict__ feat1, const float* __restrict__ feat2,
    const float* __restrict__ pos_w, const float* __restrict__ pos_b,
    const float* __restrict__ w0, const float* __restrict__ b0,
    const float* __restrict__ w1, const float* __restrict__ b1,
    const float* __restrict__ t1w, const float* __restrict__ t1b,
    const float* __restrict__ t2w, const float* __restrict__ t2b,
    const int* __restrict__ knn, float* __restrict__ out)
{
    __shared__ unsigned int T0[4][16][68];    // 17.4 KB packed activations
    __shared__ unsigned int T1[4][16][68];    // 17.4 KB
    __shared__ float sm[PTS][64];             // 4 KB pooled features (16 pts)

    const int t    = threadIdx.x;
    const int w    = t >> 6;          // wave = N-tile index 0..3
    const int lane = t & 63;
    const int m    = lane & 15;       // A-row (neighbor) / C-col (channel)
    const int quad = lane >> 4;

    const int p0  = blockIdx.x * PTS;
    const int dir = p0 >> 14, bt = (p0 >> 13) & 1;
    const int n0  = p0 & (NPTS - 1);

    const float* __restrict__ pqd = dir ? pc2 : pc1;
    const float* __restrict__ pcd = dir ? pc1 : pc2;
    const float* __restrict__ fqd = dir ? feat2 : feat1;
    const float* __restrict__ fcd = dir ? feat1 : feat2;

    // ---- per-block setup (amortized over 16 points) ------------------------
    const int ocol = w * 16 + m;               // this lane's output channel
    bf16x8 Bh[2][2], Bl[2][2];                 // [layer][ktile]
    #pragma unroll
    for (int kt = 0; kt < 2; ++kt) {
        build_b(&w0[(size_t)ocol * 64 + kt * 32 + quad * 8], &Bh[0][kt], &Bl[0][kt]);
        build_b(&w1[(size_t)ocol * 64 + kt * 32 + quad * 8], &Bh[1][kt], &Bl[1][kt]);
    }
    const float bias1 = b0[ocol];
    const float bias2 = b1[ocol];

    const int cg0 = w * 16 + quad * 4;
    float pbc[4], pwx[4], pwy[4], pwz[4];
    #pragma unroll
    for (int i = 0; i < 4; ++i) {
        pbc[i] = pos_b[cg0 + i];
        pwx[i] = pos_w[(cg0 + i) * 3 + 0];
        pwy[i] = pos_w[(cg0 + i) * 3 + 1];
        pwz[i] = pos_w[(cg0 + i) * 3 + 2];
    }

    // ---- register staging for the pipelined gather -------------------------
    float  sdx[4], sdy[4], sdz[4];
    float4 sgf[4], sfq[4];

    auto loadg = [&](int gg) {      // issue group gg's gathers into registers
        #pragma unroll
        for (int pt = 0; pt < 4; ++pt) {
            const int pp = p0 + gg * 4 + pt;
            const int nn = n0 + gg * 4 + pt;
            const int id = knn[(size_t)pp * KNNK + m];
            const float* qp  = pqd + ((size_t)bt * NPTS + nn) * 3;
            const float* nbp = pcd + ((size_t)bt * NPTS + id) * 3;
            sdx[pt] = nbp[0] - qp[0];
            sdy[pt] = nbp[1] - qp[1];
            sdz[pt] = nbp[2] - qp[2];
            sgf[pt] = *(const float4*)&fcd[((size_t)bt * NPTS + id) * 64 + cg0];
            sfq[pt] = *(const float4*)&fqd[((size_t)bt * NPTS + nn) * 64 + cg0];
        }
    };

    auto storeg = [&]() {           // initial layer from staged regs -> T0
        #pragma unroll
        for (int pt = 0; pt < 4; ++pt) {
            const float gfa[4] = {sgf[pt].x, sgf[pt].y, sgf[pt].z, sgf[pt].w};
            const float fqa[4] = {sfq[pt].x, sfq[pt].y, sfq[pt].z, sfq[pt].w};
            uint4 U;
            unsigned int* Up = (unsigned int*)&U;
            #pragma unroll
            for (int i = 0; i < 4; ++i) {
                float v = gfa[i] + fqa[i] + pbc[i];
                v = fmaf(sdx[pt], pwx[i], v);
                v = fmaf(sdy[pt], pwy[i], v);
                v = fmaf(sdz[pt], pwz[i], v);
                v = fmaxf(v, LEAKY * v);
                Up[i] = packhl(v);
            }
            *(uint4*)&T0[pt][m][cg0] = U;
        }
    };

    // ---- prologue: group 0 -------------------------------------------------
    loadg(0);
    storeg();
    __syncthreads();

    // ---- pipelined group loop ----------------------------------------------
    #pragma unroll
    for (int g = 0; g < NG; ++g) {
        if (g + 1 < NG) loadg(g + 1);   // gathers hide under B(g)+C(g)

        // ---- stage B: layer 1 (MFMA) T0 -> T1 ------------------------------
        #pragma unroll
        for (int pt = 0; pt < 4; ++pt) {
            unsigned int Tu[8];
            bf16x8 Ah, Al;
            f32x4 acc = {0.f, 0.f, 0.f, 0.f};
            #pragma unroll
            for (int kt = 0; kt < 2; ++kt) {
                *(uint4*)&Tu[0] = *(const uint4*)&T0[pt][m][kt * 32 + quad * 8];
                *(uint4*)&Tu[4] = *(const uint4*)&T0[pt][m][kt * 32 + quad * 8 + 4];
                unpack_a(Tu, &Ah, &Al);
                acc = mfma3(acc, Ah, Al, Bh[0][kt], Bl[0][kt]);
            }
            #pragma unroll
            for (int r = 0; r < 4; ++r) {
                float v = acc[r] + bias1;
                v = fmaxf(v, LEAKY * v);
                T1[pt][quad * 4 + r][ocol] = packhl(v);
            }
        }
        __syncthreads();   // all waves done reading T0(g), T1(g) visible

        if (g + 1 < NG) storeg();       // overwrite T0 with group g+1

        // ---- stage C: layer 2 (MFMA) + max-pool -> sm ----------------------
        #pragma unroll
        for (int pt = 0; pt < 4; ++pt) {
            unsigned int Tu[8];
            bf16x8 Ah, Al;
            f32x4 acc = {0.f, 0.f, 0.f, 0.f};
            #pragma unroll
            for (int kt = 0; kt < 2; ++kt) {
                *(uint4*)&Tu[0] = *(const uint4*)&T1[pt][m][kt * 32 + quad * 8];
                *(uint4*)&Tu[4] = *(const uint4*)&T1[pt][m][kt * 32 + quad * 8 + 4];
                unpack_a(Tu, &Ah, &Al);
                acc = mfma3(acc, Ah, Al, Bh[1][kt], Bl[1][kt]);
            }
            float mx = -3.0e38f;
            #pragma unroll
            for (int r = 0; r < 4; ++r) {
                float v = acc[r] + bias2;
                v = fmaxf(v, LEAKY * v);
                mx = fmaxf(mx, v);
            }
            mx = fmaxf(mx, __shfl_xor(mx, 16));
            mx = fmaxf(mx, __shfl_xor(mx, 32));
            if (quad == 0) sm[g * 4 + pt][ocol] = mx;
        }
        __syncthreads();   // T0(g+1) ready for B(g+1); sm(g) visible
    }

    // ---- stage D: final 64->128 linear, 16 points, weights loaded once -----
    {
        const float* __restrict__ tw = dir ? t2w : t1w;
        const float* __restrict__ tb = dir ? t2b : t1b;
        const int o  = t & 127;
        const int pg = t >> 7;                 // 0..1: which pairs this thread owns
        float acc[8];
        const float bz = tb[o];
        #pragma unroll
        for (int i = 0; i < 8; ++i) acc[i] = bz;
        #pragma unroll
        for (int cc = 0; cc < 64; cc += 4) {
            const float4 wq = *(const float4*)&tw[(size_t)o * 64 + cc];
            #pragma unroll
            for (int pr = 0; pr < 4; ++pr) {
                const int pa = (2 * pr + pg) * 2;       // pair -> even point
                const float4 a0 = *(const float4*)&sm[pa][cc];
                const float4 a1 = *(const float4*)&sm[pa + 1][cc];
                float x0 = acc[2 * pr], x1 = acc[2 * pr + 1];
                x0 = fmaf(a0.x, wq.x, x0); x0 = fmaf(a0.y, wq.y, x0);
                x0 = fmaf(a0.z, wq.z, x0); x0 = fmaf(a0.w, wq.w, x0);
                x1 = fmaf(a1.x, wq.x, x1); x1 = fmaf(a1.y, wq.y, x1);
                x1 = fmaf(a1.z, wq.z, x1); x1 = fmaf(a1.w, wq.w, x1);
                acc[2 * pr] = x0; acc[2 * pr + 1] = x1;
            }
        }
        float* op = out + (size_t)dir * (2 * NPTS * 128);
        #pragma unroll
        for (int pr = 0; pr < 4; ++pr) {
            const int pa = (2 * pr + pg) * 2;
            op[((size_t)bt * NPTS + n0 + pa) * 128 + o]     = acc[2 * pr];
            op[((size_t)bt * NPTS + n0 + pa + 1) * 128 + o] = acc[2 * pr + 1];
        }
    }
}

// ---------------------------------------------------------------------------
extern "C" void kernel_launch(void* const* d_in, const int* in_sizes, int n_in,
                              void* d_out, int out_size, void* d_ws, size_t ws_size,
                              hipStream_t stream)
{
    const float* pc1   = (const float*)d_in[0];
    const float* pc2   = (const float*)d_in[1];
    const float* feat1 = (const float*)d_in[2];
    const float* feat2 = (const float*)d_in[3];
    const float* pos_w = (const float*)d_in[4];
    const float* pos_b = (const float*)d_in[5];
    const float* w0    = (const float*)d_in[6];
    const float* b0    = (const float*)d_in[7];
    const float* w1    = (const float*)d_in[8];
    const float* b1    = (const float*)d_in[9];
    const float* t1w   = (const float*)d_in[10];
    const float* t1b   = (const float*)d_in[11];
    const float* t2w   = (const float*)d_in[12];
    const float* t2b   = (const float*)d_in[13];

    int*   knn = (int*)d_ws;          // 32768 * 16 ints = 2 MB scratch
    float* out = (float*)d_out;

    hipLaunchKernelGGL(knn_kernel, dim3(32768 / QPB), dim3(KTH), 0, stream,
                       pc1, pc2, knn);
    hipLaunchKernelGGL(feat_kernel, dim3(32768 / PTS), dim3(256), 0, stream,
                       pc1, pc2, feat1, feat2, pos_w, pos_b,
                       w0, b0, w1, b1, t1w, t1b, t2w, t2b, knn, out);
}

// Round 8
// 261.087 us; speedup vs baseline: 1.1236x; 1.1236x over previous
//
#include <hip/hip_runtime.h>

#define NPTS 8192
#define KNNK 16
#define NSLOT 17          // keep 17, fp64-refine drops the worst -> robust 16-set
#define LEAKY 0.1f

typedef short bf16x8 __attribute__((ext_vector_type(8)));
typedef float f32x4  __attribute__((ext_vector_type(4)));

// ---- knn config ----
#define KTH   1024             // threads/block (16 waves): 16 waves/CU, 1 blk/CU
#define QPB   128              // queries per block -> grid 256
#define CHN   64               // chunks (threads) per query, 128 cands each
#define GQ    8                // queries per thread
#define JPX   (NPTS / (CHN * 4))   // 32 iters, 4 adjacent candidates per thread
#define BUFCAP 48              // survivor buffer per query

// ---------------------------------------------------------------------------
// R12: revert R11's MFMA distances (latency-chained ds_read->mfma->mfma->med3
// with 4/32 K-efficiency regressed 129.5->149.7us; reduction-shaped work
// stays on VALU). Back to R9 structure with two arithmetic cuts:
// (1) phase 1 keeps min-1 per chunk only — rank-17 of ANY chunk-minima table
//     is a valid upper bound on d16 (concentration makes it looser, never
//     unsafe), so the fmed3 min-2 tracking is unnecessary for the threshold.
// (2) GQ=8 / CHN=64: candidate-norm amortized over 8 queries (0.4 op/pair),
//     each candidate LDS-read shared by 16 threads (was 32) -> hot-loop
//     ds_read traffic halves. Phase-1 VALU/pair 5.75 -> 4.4.
// Threshold tightness improves (64 chunk-mins of 128 -> E[survivors]~20).
// Survivor buffer, exact fp32 d' at collect, phase-3 top-17 + fp64 refine
// byte-identical to R9's passing kernel.
// ---------------------------------------------------------------------------
__global__ __launch_bounds__(KTH, 4) void knn_kernel(
    const float* __restrict__ pc1, const float* __restrict__ pc2,
    int* __restrict__ knn_out)
{
    __shared__ float sx[NPTS], sy[NPTS], sz[NPTS];   // 96 KB candidate SoA
    // per-query row of 96 floats: [0..47] survd, [48..95] survi (as int).
    // cols [0..63] double as the chunk-min rank table before phase 2
    // (rows are wave-local: row qg*8+g is written/read by wave qg only).
    __shared__ float sbuf[QPB][2 * BUFCAP];          // 48 KB
    __shared__ float sthr[QPB];
    __shared__ int   scnt[QPB];

    const int t   = threadIdx.x;
    const int q0  = blockIdx.x * QPB;
    const int dir = q0 >> 14;
    const int b   = (q0 >> 13) & 1;

    const float* __restrict__ pq    = dir ? pc2 : pc1;
    const float* __restrict__ pcand = dir ? pc1 : pc2;

    const float* src = pcand + (size_t)b * NPTS * 3;
    for (int i = t; i < NPTS; i += KTH) {
        sx[i] = src[3 * i];
        sy[i] = src[3 * i + 1];
        sz[i] = src[3 * i + 2];
    }
    if (t < QPB) scnt[t] = 0;
    __syncthreads();

    const int ch = t & (CHN - 1);      // chunk 0..63
    const int qg = t >> 6;             // query group == wave 0..15 (8 queries)
    const int n0 = q0 & (NPTS - 1);

    // q2 = -2*q ; |q|^2 dropped (constant per query, ordering preserved)
    float q2x[GQ], q2y[GQ], q2z[GQ];
    #pragma unroll
    for (int g = 0; g < GQ; ++g) {
        const float* qp = pq + ((size_t)b * NPTS + n0 + qg * GQ + g) * 3;
        q2x[g] = -2.0f * qp[0];
        q2y[g] = -2.0f * qp[1];
        q2z[g] = -2.0f * qp[2];
    }

    // ---- phase 1: min-1 per (thread,query) ---------------------------------
    float m1[GQ];
    #pragma unroll
    for (int g = 0; g < GQ; ++g) m1[g] = 3.0e38f;

    #pragma unroll 2
    for (int j = 0; j < JPX; ++j) {
        const int i0 = j * (CHN * 4) + 4 * ch;
        const f32x4 cx = *(const f32x4*)&sx[i0];
        const f32x4 cy = *(const f32x4*)&sy[i0];
        const f32x4 cz = *(const f32x4*)&sz[i0];
        f32x4 cn;
        #pragma unroll
        for (int c = 0; c < 4; ++c)
            cn[c] = fmaf(cx[c], cx[c], fmaf(cy[c], cy[c], cz[c] * cz[c]));
        #pragma unroll
        for (int g = 0; g < GQ; ++g) {
            #pragma unroll
            for (int c = 0; c < 4; ++c) {
                const float d = fmaf(q2x[g], cx[c],
                                fmaf(q2y[g], cy[c],
                                fmaf(q2z[g], cz[c], cn[c])));
                m1[g] = fminf(m1[g], d);
            }
        }
    }

    // ---- threshold: 17th-smallest of the 64 chunk-mins ---------------------
    // Valid upper bound on true d16: each of the true top-17 lies in some
    // chunk whose min is <= it; concentration only raises the table's
    // rank-17. Phase 2 therefore collects a superset of the true top-17.
    #pragma unroll
    for (int g = 0; g < GQ; ++g)
        sbuf[qg * GQ + g][ch] = m1[g];
    __builtin_amdgcn_wave_barrier();   // table rows are wave-local

    #pragma unroll
    for (int g = 0; g < GQ; ++g) {
        const int row = qg * GQ + g;
        const float v1 = m1[g];
        int lt = 0, eq = 0;
        #pragma unroll
        for (int c = 0; c < CHN; c += 2) {
            const float2 vp = *(const float2*)&sbuf[row][c];
            lt += (vp.x < v1) ? 1 : 0;  eq += (vp.x == v1) ? 1 : 0;
            lt += (vp.y < v1) ? 1 : 0;  eq += (vp.y == v1) ? 1 : 0;
        }
        // value of rank 16 (0-based): lt <= 16 < lt+eq. Ties all write
        // identical bits — benign.
        if (lt <= 16 && lt + eq > 16) sthr[row] = v1;
    }
    __builtin_amdgcn_wave_barrier();

    // ---- phase 2: collect survivors (exact fp32 d' stored) -----------------
    float tq[GQ];
    #pragma unroll
    for (int g = 0; g < GQ; ++g) tq[g] = sthr[qg * GQ + g];

    #pragma unroll 2
    for (int j = 0; j < JPX; ++j) {
        const int i0 = j * (CHN * 4) + 4 * ch;
        const f32x4 cx = *(const f32x4*)&sx[i0];
        const f32x4 cy = *(const f32x4*)&sy[i0];
        const f32x4 cz = *(const f32x4*)&sz[i0];
        f32x4 cn;
        #pragma unroll
        for (int c = 0; c < 4; ++c)
            cn[c] = fmaf(cx[c], cx[c], fmaf(cy[c], cy[c], cz[c] * cz[c]));
        #pragma unroll
        for (int g = 0; g < GQ; ++g) {
            #pragma unroll
            for (int c = 0; c < 4; ++c) {
                const float d = fmaf(q2x[g], cx[c],
                                fmaf(q2y[g], cy[c],
                                fmaf(q2z[g], cz[c], cn[c])));
                if (d <= tq[g]) {
                    const int q = qg * GQ + g;
                    const int pos = atomicAdd(&scnt[q], 1);
                    if (pos < BUFCAP) {
                        sbuf[q][pos] = d;
                        ((int*)&sbuf[q][BUFCAP])[pos] = i0 + c;
                    }
                }
            }
        }
    }
    __syncthreads();

    // ---- phase 3: exact top-17 of survivors + fp64 refine ------------------
    if (t < QPB) {
        const int nc = min(scnt[t], BUFCAP);

        float dist[NSLOT];   // sorted descending by (d, idx); dist[0] = worst
        int   ind[NSLOT];
        #pragma unroll
        for (int i = 0; i < NSLOT; ++i) { dist[i] = 3.0e38f; ind[i] = 0x7fffffff; }

        for (int s = 0; s < nc; ++s) {
            const float d  = sbuf[t][s];
            const int   id = ((int*)&sbuf[t][BUFCAP])[s];
            const bool better0 = (d < dist[0]) || (d == dist[0] && id < ind[0]);
            if (better0) {
                bool cprev = true;
                #pragma unroll
                for (int i = 0; i < NSLOT - 1; ++i) {
                    const bool ci = (d < dist[i + 1]) ||
                                    (d == dist[i + 1] && id < ind[i + 1]);
                    const float nv = ci ? dist[i + 1] : (cprev ? d  : dist[i]);
                    const int   ni = ci ? ind[i + 1]  : (cprev ? id : ind[i]);
                    dist[i] = nv; ind[i] = ni;
                    cprev = ci;
                }
                if (cprev) { dist[NSLOT - 1] = d; ind[NSLOT - 1] = id; }
            }
        }

        const float* qpp = pq + ((size_t)b * NPTS + n0 + t) * 3;
        const double dqx = (double)qpp[0], dqy = (double)qpp[1], dqz = (double)qpp[2];
        double dd[NSLOT];
        #pragma unroll
        for (int i = 0; i < NSLOT; ++i) {
            const int id = ind[i];
            const double dx = (double)sx[id] - dqx;
            const double dy = (double)sy[id] - dqy;
            const double dz = (double)sz[id] - dqz;
            dd[i] = dx * dx + dy * dy + dz * dz;
        }
        int worst = 0; double wd = dd[0];
        #pragma unroll
        for (int i = 1; i < NSLOT; ++i) { if (dd[i] > wd) { wd = dd[i]; worst = i; } }

        int* outp = knn_out + (size_t)(q0 + t) * KNNK;
        int slot = 0;
        #pragma unroll
        for (int i = 0; i < NSLOT; ++i) {
            if (i != worst) outp[slot++] = ind[i];
        }
    }
}

// ---------------------------------------------------------------------------
// Kernel 2 (R10, unchanged): feature MLP, 16 points/block in 4 pipelined
// groups of 4 with register-staged gather overlap.
// ---------------------------------------------------------------------------
#define PTS 16     // points per block
#define NG  4      // groups of 4 points

__device__ __forceinline__ unsigned int packhl(float f) {
    const unsigned int u = __float_as_uint(f);
    const unsigned int h = u & 0xffff0000u;
    const float lf = f - __uint_as_float(h);
    return h | (__float_as_uint(lf) >> 16);
}

__device__ __forceinline__ void build_b(const float* __restrict__ wrow,
                                        bf16x8* hi, bf16x8* lo) {
    union { unsigned int u[4]; bf16x8 v; } H, L;
    #pragma unroll
    for (int r = 0; r < 4; ++r) {
        const float f0 = wrow[2 * r], f1 = wrow[2 * r + 1];
        const unsigned int h0 = __float_as_uint(f0) & 0xffff0000u;
        const unsigned int h1 = __float_as_uint(f1) & 0xffff0000u;
        const float l0 = f0 - __uint_as_float(h0);
        const float l1 = f1 - __uint_as_float(h1);
        H.u[r] = h1 | (h0 >> 16);
        L.u[r] = (__float_as_uint(l1) & 0xffff0000u) | (__float_as_uint(l0) >> 16);
    }
    *hi = H.v; *lo = L.v;
}

__device__ __forceinline__ void unpack_a(const unsigned int* __restrict__ Tu,
                                         bf16x8* hi, bf16x8* lo) {
    union { unsigned int u[4]; bf16x8 v; } H, L;
    #pragma unroll
    for (int r = 0; r < 4; ++r) {
        const unsigned int a = Tu[2 * r + 1], bb = Tu[2 * r];
        H.u[r] = __builtin_amdgcn_perm(a, bb, 0x07060302u);  // [a.hi16 : b.hi16]
        L.u[r] = __builtin_amdgcn_perm(a, bb, 0x05040100u);  // [a.lo16 : b.lo16]
    }
    *hi = H.v; *lo = L.v;
}

__device__ __forceinline__ f32x4 mfma3(f32x4 acc, bf16x8 ah, bf16x8 al,
                                       bf16x8 bh, bf16x8 bl) {
    acc = __builtin_amdgcn_mfma_f32_16x16x32_bf16(ah, bl, acc, 0, 0, 0);
    acc = __builtin_amdgcn_mfma_f32_16x16x32_bf16(al, bh, acc, 0, 0, 0);
    acc = __builtin_amdgcn_mfma_f32_16x16x32_bf16(ah, bh, acc, 0, 0, 0);
    return acc;
}

__global__ __launch_bounds__(256, 4) void feat_kernel(
    const float* __restrict__ pc1, const float* __restrict__ pc2,
    const float* __restrict__ feat1, const float* __restrict__ feat2,
    const float* __restrict__ pos_w, const float* __restrict__ pos_b,
    const float* __restrict__ w0, const float* __restrict__ b0,
    const float* __restrict__ w1, const float* __restrict__ b1,
    const float* __restrict__ t1w, const float* __restrict__ t1b,
    const float* __restrict__ t2w, const float* __restrict__ t2b,
    const int* __restrict__ knn, float* __restrict__ out)
{
    __shared__ unsigned int T0[4][16][68];    // 17.4 KB packed activations
    __shared__ unsigned int T1[4][16][68];    // 17.4 KB
    __shared__ float sm[PTS][64];             // 4 KB pooled features (16 pts)

    const int t    = threadIdx.x;
    const int w    = t >> 6;          // wave = N-tile index 0..3
    const int lane = t & 63;
    const int m    = lane & 15;       // A-row (neighbor) / C-col (channel)
    const int quad = lane >> 4;

    const int p0  = blockIdx.x * PTS;
    const int dir = p0 >> 14, bt = (p0 >> 13) & 1;
    const int n0  = p0 & (NPTS - 1);

    const float* __restrict__ pqd = dir ? pc2 : pc1;
    const float* __restrict__ pcd = dir ? pc1 : pc2;
    const float* __restrict__ fqd = dir ? feat2 : feat1;
    const float* __restrict__ fcd = dir ? feat1 : feat2;

    // ---- per-block setup (amortized over 16 points) ------------------------
    const int ocol = w * 16 + m;               // this lane's output channel
    bf16x8 Bh[2][2], Bl[2][2];                 // [layer][ktile]
    #pragma unroll
    for (int kt = 0; kt < 2; ++kt) {
        build_b(&w0[(size_t)ocol * 64 + kt * 32 + quad * 8], &Bh[0][kt], &Bl[0][kt]);
        build_b(&w1[(size_t)ocol * 64 + kt * 32 + quad * 8], &Bh[1][kt], &Bl[1][kt]);
    }
    const float bias1 = b0[ocol];
    const float bias2 = b1[ocol];

    const int cg0 = w * 16 + quad * 4;
    float pbc[4], pwx[4], pwy[4], pwz[4];
    #pragma unroll
    for (int i = 0; i < 4; ++i) {
        pbc[i] = pos_b[cg0 + i];
        pwx[i] = pos_w[(cg0 + i) * 3 + 0];
        pwy[i] = pos_w[(cg0 + i) * 3 + 1];
        pwz[i] = pos_w[(cg0 + i) * 3 + 2];
    }

    // ---- register staging for the pipelined gather -------------------------
    float  sdx[4], sdy[4], sdz[4];
    float4 sgf[4], sfq[4];

    auto loadg = [&](int gg) {      // issue group gg's gathers into registers
        #pragma unroll
        for (int pt = 0; pt < 4; ++pt) {
            const int pp = p0 + gg * 4 + pt;
            const int nn = n0 + gg * 4 + pt;
            const int id = knn[(size_t)pp * KNNK + m];
            const float* qp  = pqd + ((size_t)bt * NPTS + nn) * 3;
            const float* nbp = pcd + ((size_t)bt * NPTS + id) * 3;
            sdx[pt] = nbp[0] - qp[0];
            sdy[pt] = nbp[1] - qp[1];
            sdz[pt] = nbp[2] - qp[2];
            sgf[pt] = *(const float4*)&fcd[((size_t)bt * NPTS + id) * 64 + cg0];
            sfq[pt] = *(const float4*)&fqd[((size_t)bt * NPTS + nn) * 64 + cg0];
        }
    };

    auto storeg = [&]() {           // initial layer from staged regs -> T0
        #pragma unroll
        for (int pt = 0; pt < 4; ++pt) {
            const float gfa[4] = {sgf[pt].x, sgf[pt].y, sgf[pt].z, sgf[pt].w};
            const float fqa[4] = {sfq[pt].x, sfq[pt].y, sfq[pt].z, sfq[pt].w};
            uint4 U;
            unsigned int* Up = (unsigned int*)&U;
            #pragma unroll
            for (int i = 0; i < 4; ++i) {
                float v = gfa[i] + fqa[i] + pbc[i];
                v = fmaf(sdx[pt], pwx[i], v);
                v = fmaf(sdy[pt], pwy[i], v);
                v = fmaf(sdz[pt], pwz[i], v);
                v = fmaxf(v, LEAKY * v);
                Up[i] = packhl(v);
            }
            *(uint4*)&T0[pt][m][cg0] = U;
        }
    };

    // ---- prologue: group 0 -------------------------------------------------
    loadg(0);
    storeg();
    __syncthreads();

    // ---- pipelined group loop ----------------------------------------------
    #pragma unroll
    for (int g = 0; g < NG; ++g) {
        if (g + 1 < NG) loadg(g + 1);   // gathers hide under B(g)+C(g)

        // ---- stage B: layer 1 (MFMA) T0 -> T1 ------------------------------
        #pragma unroll
        for (int pt = 0; pt < 4; ++pt) {
            unsigned int Tu[8];
            bf16x8 Ah, Al;
            f32x4 acc = {0.f, 0.f, 0.f, 0.f};
            #pragma unroll
            for (int kt = 0; kt < 2; ++kt) {
                *(uint4*)&Tu[0] = *(const uint4*)&T0[pt][m][kt * 32 + quad * 8];
                *(uint4*)&Tu[4] = *(const uint4*)&T0[pt][m][kt * 32 + quad * 8 + 4];
                unpack_a(Tu, &Ah, &Al);
                acc = mfma3(acc, Ah, Al, Bh[0][kt], Bl[0][kt]);
            }
            #pragma unroll
            for (int r = 0; r < 4; ++r) {
                float v = acc[r] + bias1;
                v = fmaxf(v, LEAKY * v);
                T1[pt][quad * 4 + r][ocol] = packhl(v);
            }
        }
        __syncthreads();   // all waves done reading T0(g), T1(g) visible

        if (g + 1 < NG) storeg();       // overwrite T0 with group g+1

        // ---- stage C: layer 2 (MFMA) + max-pool -> sm ----------------------
        #pragma unroll
        for (int pt = 0; pt < 4; ++pt) {
            unsigned int Tu[8];
            bf16x8 Ah, Al;
            f32x4 acc = {0.f, 0.f, 0.f, 0.f};
            #pragma unroll
            for (int kt = 0; kt < 2; ++kt) {
                *(uint4*)&Tu[0] = *(const uint4*)&T1[pt][m][kt * 32 + quad * 8];
                *(uint4*)&Tu[4] = *(const uint4*)&T1[pt][m][kt * 32 + quad * 8 + 4];
                unpack_a(Tu, &Ah, &Al);
                acc = mfma3(acc, Ah, Al, Bh[1][kt], Bl[1][kt]);
            }
            float mx = -3.0e38f;
            #pragma unroll
            for (int r = 0; r < 4; ++r) {
                float v = acc[r] + bias2;
                v = fmaxf(v, LEAKY * v);
                mx = fmaxf(mx, v);
            }
            mx = fmaxf(mx, __shfl_xor(mx, 16));
            mx = fmaxf(mx, __shfl_xor(mx, 32));
            if (quad == 0) sm[g * 4 + pt][ocol] = mx;
        }
        __syncthreads();   // T0(g+1) ready for B(g+1); sm(g) visible
    }

    // ---- stage D: final 64->128 linear, 16 points, weights loaded once -----
    {
        const float* __restrict__ tw = dir ? t2w : t1w;
        const float* __restrict__ tb = dir ? t2b : t1b;
        const int o  = t & 127;
        const int pg = t >> 7;                 // 0..1: which pairs this thread owns
        float acc[8];
        const float bz = tb[o];
        #pragma unroll
        for (int i = 0; i < 8; ++i) acc[i] = bz;
        #pragma unroll
        for (int cc = 0; cc < 64; cc += 4) {
            const float4 wq = *(const float4*)&tw[(size_t)o * 64 + cc];
            #pragma unroll
            for (int pr = 0; pr < 4; ++pr) {
                const int pa = (2 * pr + pg) * 2;       // pair -> even point
                const float4 a0 = *(const float4*)&sm[pa][cc];
                const float4 a1 = *(const float4*)&sm[pa + 1][cc];
                float x0 = acc[2 * pr], x1 = acc[2 * pr + 1];
                x0 = fmaf(a0.x, wq.x, x0); x0 = fmaf(a0.y, wq.y, x0);
                x0 = fmaf(a0.z, wq.z, x0); x0 = fmaf(a0.w, wq.w, x0);
                x1 = fmaf(a1.x, wq.x, x1); x1 = fmaf(a1.y, wq.y, x1);
                x1 = fmaf(a1.z, wq.z, x1); x1 = fmaf(a1.w, wq.w, x1);
                acc[2 * pr] = x0; acc[2 * pr + 1] = x1;
            }
        }
        float* op = out + (size_t)dir * (2 * NPTS * 128);
        #pragma unroll
        for (int pr = 0; pr < 4; ++pr) {
            const int pa = (2 * pr + pg) * 2;
            op[((size_t)bt * NPTS + n0 + pa) * 128 + o]     = acc[2 * pr];
            op[((size_t)bt * NPTS + n0 + pa + 1) * 128 + o] = acc[2 * pr + 1];
        }
    }
}

// ---------------------------------------------------------------------------
extern "C" void kernel_launch(void* const* d_in, const int* in_sizes, int n_in,
                              void* d_out, int out_size, void* d_ws, size_t ws_size,
                              hipStream_t stream)
{
    const float* pc1   = (const float*)d_in[0];
    const float* pc2   = (const float*)d_in[1];
    const float* feat1 = (const float*)d_in[2];
    const float* feat2 = (const float*)d_in[3];
    const float* pos_w = (const float*)d_in[4];
    const float* pos_b = (const float*)d_in[5];
    const float* w0    = (const float*)d_in[6];
    const float* b0    = (const float*)d_in[7];
    const float* w1    = (const float*)d_in[8];
    const float* b1    = (const float*)d_in[9];
    const float* t1w   = (const float*)d_in[10];
    const float* t1b   = (const float*)d_in[11];
    const float* t2w   = (const float*)d_in[12];
    const float* t2b   = (const float*)d_in[13];

    int*   knn = (int*)d_ws;          // 32768 * 16 ints = 2 MB scratch
    float* out = (float*)d_out;

    hipLaunchKernelGGL(knn_kernel, dim3(32768 / QPB), dim3(KTH), 0, stream,
                       pc1, pc2, knn);
    hipLaunchKernelGGL(feat_kernel, dim3(32768 / PTS), dim3(256), 0, stream,
                       pc1, pc2, feat1, feat2, pos_w, pos_b,
                       w0, b0, w1, b1, t1w, t1b, t2w, t2b, knn, out);
}